// Round 21
// baseline (68.354 us; speedup 1.0000x reference)
//
#include <hip/hip_runtime.h>
#include <hip/hip_bf16.h>

typedef __attribute__((ext_vector_type(4))) float f32x4;
typedef __attribute__((ext_vector_type(4))) int i32x4;
typedef __attribute__((ext_vector_type(2))) int i32x2;

#define BSZ   8192
#define DDIM  128
#define NCLS  512
#define SLOT  48                    // max members/class supported (actual max ~34)
#define NPAN  64                    // 128-row panels
#define NTRI  (NPAN * (NPAN + 1) / 2)   // 2080 upper-triangular 128x128 tiles

#define L2E  1.44269504088896340736f
#define RLN2 0.69314718055994530942f

static __device__ __forceinline__ float fast_sqrt(float x) {
  float r; asm("v_sqrt_f32 %0, %1" : "=v"(r) : "v"(x)); return r;
}
static __device__ __forceinline__ float fast_exp2(float x) {
  float r; asm("v_exp_f32 %0, %1" : "=v"(r) : "v"(x)); return r;
}
static __device__ __forceinline__ float fast_log2(float x) {
  float r; asm("v_log_f32 %0, %1" : "=v"(r) : "v"(x)); return r;
}

static __device__ __forceinline__ void tile_ij(int t, int& bi, int& bj) {
  int j = (int)((sqrtf(8.0f * (float)t + 1.0f) - 1.0f) * 0.5f);
  while ((j + 1) * (j + 2) / 2 <= t) ++j;
  while (j * (j + 1) / 2 > t) --j;
  bi = t - j * (j + 1) / 2;
  bj = j;
}

// Decode unordered-pair linear index u -> (i, j) with j > i, for n rows.
static __device__ __forceinline__ void pair_ij(int u, int n, int& pi, int& pj) {
  float fn = (float)(2 * n - 1);
  int i = (int)((fn - fast_sqrt(fn * fn - 8.0f * (float)u)) * 0.5f);
  if (i < 0) i = 0;
  while ((i + 1) * (2 * n - i - 2) / 2 <= u) ++i;
  while (i * (2 * n - i - 1) / 2 > u) --i;
  pi = i;
  pj = i + 1 + (u - i * (2 * n - i - 1) / 2);
}

// score -> fp8(e4m3) in MFMA-FRAGMENT order + exact fp32 row magnitudes.
// Also zeroes the class ticket. (measured: 1.9 us)
__global__ void prep_kernel(const float* __restrict__ score,
                            unsigned char* __restrict__ Sfrag,
                            float* __restrict__ mag,
                            int* __restrict__ ticket) {
  int gid = blockIdx.x * 256 + threadIdx.x;   // 131072 threads
  if (gid == 0) *ticket = 0;
  int row = gid >> 4, sub = gid & 15;
  const f32x4* src = (const f32x4*)(score + (size_t)row * DDIM + sub * 8);
  f32x4 a = src[0], b = src[1];
  i32x2 pk;
  int w0 = 0, w1 = 0;
  w0 = __builtin_amdgcn_cvt_pk_fp8_f32(a[0], a[1], w0, false);
  w0 = __builtin_amdgcn_cvt_pk_fp8_f32(a[2], a[3], w0, true);
  w1 = __builtin_amdgcn_cvt_pk_fp8_f32(b[0], b[1], w1, false);
  w1 = __builtin_amdgcn_cvt_pk_fp8_f32(b[2], b[3], w1, true);
  pk[0] = w0; pk[1] = w1;
  size_t chunk = ((size_t)(row >> 4) * 4 + (sub >> 2)) * 64
               + (size_t)(sub & 3) * 16 + (row & 15);
  ((i32x2*)Sfrag)[chunk] = pk;
  float sq = a[0]*a[0] + a[1]*a[1] + a[2]*a[2] + a[3]*a[3]
           + b[0]*b[0] + b[1]*b[1] + b[2]*b[2] + b[3]*b[3];
  sq += __shfl_xor(sq, 1); sq += __shfl_xor(sq, 2);
  sq += __shfl_xor(sq, 4); sq += __shfl_xor(sq, 8);
  if (sub == 0) mag[row] = sq;
}

// Dense symmetric pass (R17 body; measured 21.7 us). MEASUREMENT ROUND:
// grid doubled (blockIdx % NTRI) so the dispatch (~43 us) ranks above the
// harness poison fills and exposes counters. Duplicate blocks write
// identical values to the same P slots (benign race).
__launch_bounds__(512, 8)
__global__ void dense_pass(const unsigned char* __restrict__ Sfrag,
                           const float* __restrict__ mag,
                           float* __restrict__ P) {
  int t = blockIdx.x;
  if (t >= NTRI) t -= NTRI;
  int bi, bj; tile_ij(t, bi, bj);
  const int i0 = bi * 128, j0 = bj * 128;
  const bool diag = (bi == bj);

  __shared__ float Lrow[128][4];
  __shared__ float Lcol[128][2];

  const int tid = threadIdx.x;
  const int wid = tid >> 6, l = tid & 63;
  const int wr = wid >> 2, wc = wid & 3;       // 2x4 wave grid: 64x32 tiles
  const int lr = l >> 4, lc = l & 15;

  const long* F = (const long*)Sfrag;          // one long = one 8B chunk
  const int pa = (i0 >> 4) + wr * 4;           // A panel16 base
  const int pb = (j0 >> 4) + wc * 2;           // B panel16 base

  f32x4 acc[4][2] = {};
  #pragma unroll
  for (int ks = 0; ks < 4; ++ks) {
    long af[4], bfr[2];
    #pragma unroll
    for (int m = 0; m < 4; ++m)
      af[m] = F[(size_t)((pa + m) * 4 + ks) * 64 + l];
    #pragma unroll
    for (int n = 0; n < 2; ++n)
      bfr[n] = F[(size_t)((pb + n) * 4 + ks) * 64 + l];
    #pragma unroll
    for (int m = 0; m < 4; ++m)
      #pragma unroll
      for (int n = 0; n < 2; ++n)
        acc[m][n] = __builtin_amdgcn_mfma_f32_16x16x32_fp8_fp8(
            af[m], bfr[n], acc[m][n], 0, 0, 0);
  }

  const float magj0 = mag[j0 + wc * 32 + lc];
  const float magj1 = mag[j0 + wc * 32 + 16 + lc];
  float cs0 = 0.0f, cs1 = 0.0f;

  #pragma unroll
  for (int m = 0; m < 4; ++m) {
    const f32x4 mi = *(const f32x4*)&mag[i0 + wr * 64 + m * 16 + lr * 4];
    #pragma unroll
    for (int rg = 0; rg < 4; ++rg) {
      // C layout: col = lane&15, row = (lane>>4)*4 + reg
      const int rrow = wr * 64 + m * 16 + lr * 4 + rg;
      float d2a = fmaxf(mi[rg] + magj0 - 2.0f * acc[m][0][rg], 0.0f);
      float e0 = fast_exp2(__builtin_fmaf(-L2E, fast_sqrt(d2a), L2E));
      float d2b = fmaxf(mi[rg] + magj1 - 2.0f * acc[m][1][rg], 0.0f);
      float e1 = fast_exp2(__builtin_fmaf(-L2E, fast_sqrt(d2b), L2E));
      if (diag) {
        if (rrow == wc * 32 + lc) e0 = 0.0f;        // exclude i == j
        if (rrow == wc * 32 + 16 + lc) e1 = 0.0f;
      }
      cs0 += e0; cs1 += e1;
      float v = e0 + e1;
      v += __shfl_xor(v, 1); v += __shfl_xor(v, 2);
      v += __shfl_xor(v, 4); v += __shfl_xor(v, 8);
      if (lc == 0) Lrow[rrow][wc] = v;
    }
  }
  if (!diag) {
    float v0 = cs0, v1 = cs1;
    v0 += __shfl_xor(v0, 16); v0 += __shfl_xor(v0, 32);
    v1 += __shfl_xor(v1, 16); v1 += __shfl_xor(v1, 32);
    if (lr == 0) {
      Lcol[wc * 32 + lc][wr] = v0;
      Lcol[wc * 32 + 16 + lc][wr] = v1;
    }
  }
  __syncthreads();
  float* Pt = P + (size_t)t * 256;
  if (tid < 128)
    Pt[tid] = Lrow[tid][0] + Lrow[tid][1] + Lrow[tid][2] + Lrow[tid][3];
  else if (tid < 256 && !diag)
    Pt[tid] = Lcol[tid - 128][0] + Lcol[tid - 128][1];
}

// Per-class pass + final reduce (byte-identical to R17; measured 15.9 us).
__launch_bounds__(512)
__global__ void class_pass(const float* __restrict__ score,
                           const float* __restrict__ mag,
                           const float* __restrict__ P,
                           const int* __restrict__ targets,
                           float* __restrict__ partial,
                           int* __restrict__ ticket,
                           float* __restrict__ out) {
  const int c = blockIdx.x;
  const int tid = threadIdx.x;
  __shared__ int mem[SLOT];
  __shared__ int nCnt;
  __shared__ int lastFlag;
  __shared__ float rows[SLOT][132];   // [.][128] holds mag
  __shared__ float Nf[SLOT];
  __shared__ float Ns[SLOT];
  __shared__ float dmat[SLOT * SLOT];
  __shared__ float redL[8], redC[8];

  if (tid == 0) nCnt = 0;
  __syncthreads();
  // member discovery: vectorized coalesced scan + LDS atomic append
  for (int rd = 0; rd < BSZ / 2048; ++rd) {
    int v4 = rd * 512 + tid;
    i32x4 tv = ((const i32x4*)targets)[v4];
    #pragma unroll
    for (int q = 0; q < 4; ++q) {
      if (tv[q] == c) {
        int p = atomicAdd(&nCnt, 1);
        if (p < SLOT) mem[p] = v4 * 4 + q;
      }
    }
  }
  __syncthreads();
  const int n = nCnt < SLOT ? nCnt : SLOT;

  float ll = 0.0f, lcn = 0.0f;
  if (n >= 2) {
    for (int i = tid; i < n; i += 512) { Ns[i] = 0.0f; Nf[i] = 0.0f; }
    __syncthreads();
    for (int w = tid; w < n * 32; w += 512) {
      int i = w >> 5, ch = w & 31;
      *(f32x4*)&rows[i][ch * 4] =
          *(const f32x4*)(score + (size_t)mem[i] * DDIM + ch * 4);
    }
    for (int i = tid; i < n; i += 512) rows[i][128] = mag[mem[i]];
    // gather Nfull from the 64 panel partials per member
    for (int w = tid; w < n * 64; w += 512) {
      int i = w >> 6, q = w & 63;
      int gi = mem[i], pp = gi >> 7, off = gi & 127;
      float v = (q >= pp) ? P[(size_t)(q * (q + 1) / 2 + pp) * 256 + off]
                          : P[(size_t)(pp * (pp + 1) / 2 + q) * 256 + 128 + off];
      atomicAdd(&Nf[i], v);
    }
    __syncthreads();
    const int npu = n * (n - 1) / 2;          // unordered pairs, j > i
    for (int u = tid; u < npu; u += 512) {
      int i, j; pair_ij(u, n, i, j);
      float dot = 0.0f;
      #pragma unroll
      for (int k = 0; k < 32; ++k) {
        f32x4 a = *(const f32x4*)&rows[i][k * 4];
        f32x4 b = *(const f32x4*)&rows[j][k * 4];
        dot += a[0]*b[0] + a[1]*b[1] + a[2]*b[2] + a[3]*b[3];
      }
      float d2 = fmaxf(rows[i][128] + rows[j][128] - 2.0f * dot, 0.0f);
      float dd = fast_sqrt(d2);
      dmat[i * SLOT + j] = dd;
      float e = fast_exp2(__builtin_fmaf(-L2E, dd, L2E));
      atomicAdd(&Ns[i], e);
      atomicAdd(&Ns[j], e);
    }
    __syncthreads();
    for (int i = tid; i < n; i += 512) Nf[i] -= Ns[i];
    __syncthreads();
    for (int u = tid; u < npu; u += 512) {
      int i, j; pair_ij(u, n, i, j);
      float ln = fast_log2(Nf[i] + Nf[j]) * RLN2 + dmat[i * SLOT + j];
      if (ln > 0.0f) ll += 2.0f * ln * ln;    // both orientations
      lcn += 2.0f;
    }
  }
  #pragma unroll
  for (int m = 1; m < 64; m <<= 1) {
    ll  += __shfl_xor(ll, m);
    lcn += __shfl_xor(lcn, m);
  }
  if ((tid & 63) == 0) { redL[tid >> 6] = ll; redC[tid >> 6] = lcn; }
  __syncthreads();
  if (tid == 0) {
    float sl = 0.0f, sc = 0.0f;
    #pragma unroll
    for (int w = 0; w < 8; ++w) { sl += redL[w]; sc += redC[w]; }
    partial[2 * c]     = sl;
    partial[2 * c + 1] = sc;
    __threadfence();
    lastFlag = (atomicAdd(ticket, 1) == NCLS - 1);
  }
  __syncthreads();
  if (lastFlag) {
    float sl = 0.0f, sc = 0.0f;
    for (int i = tid; i < NCLS; i += 512) {
      sl += atomicAdd(&partial[2 * i], 0.0f);       // device-scope reads
      sc += atomicAdd(&partial[2 * i + 1], 0.0f);
    }
    #pragma unroll
    for (int m = 1; m < 64; m <<= 1) {
      sl += __shfl_xor(sl, m);
      sc += __shfl_xor(sc, m);
    }
    if ((tid & 63) == 0) { redL[tid >> 6] = sl; redC[tid >> 6] = sc; }
    __syncthreads();
    if (tid == 0) {
      float L = 0.0f, C = 0.0f;
      #pragma unroll
      for (int w = 0; w < 8; ++w) { L += redL[w]; C += redC[w]; }
      out[0] = L / (4.0f * C);
    }
  }
}

extern "C" void kernel_launch(void* const* d_in, const int* in_sizes, int n_in,
                              void* d_out, int out_size, void* d_ws, size_t ws_size,
                              hipStream_t stream) {
  const float* score = (const float*)d_in[0];
  const int* targets = (const int*)d_in[1];
  float* out = (float*)d_out;

  char* ws = (char*)d_ws;
  size_t cur = 0;
  auto alloc = [&](size_t bytes) -> void* {
    void* p = ws + cur;
    cur += (bytes + 255) & ~(size_t)255;
    return p;
  };
  unsigned char* Sfrag = (unsigned char*)alloc((size_t)BSZ * DDIM);
  float* mag     = (float*)alloc(BSZ * 4);
  float* P       = (float*)alloc((size_t)NTRI * 256 * 4);
  float* partial = (float*)alloc(NCLS * 2 * 4);
  int*   ticket  = (int*)alloc(4);

  prep_kernel<<<BSZ * 16 / 256, 256, 0, stream>>>(score, Sfrag, mag, ticket);
  // MEASUREMENT: dense grid x2 -> ~43us dispatch ranks above the ~40us
  // harness fills -> counters finally visible. See prediction fork.
  dense_pass<<<NTRI * 2, 512, 0, stream>>>(Sfrag, mag, P);
  class_pass<<<NCLS, 512, 0, stream>>>(score, mag, P, targets,
                                       partial, ticket, out);
}

// Round 22
// 55.063 us; speedup vs baseline: 1.2414x; 1.2414x over previous
//
#include <hip/hip_runtime.h>
#include <hip/hip_bf16.h>

typedef __attribute__((ext_vector_type(4))) float f32x4;
typedef __attribute__((ext_vector_type(2))) float f32x2;
typedef __attribute__((ext_vector_type(4))) int i32x4;
typedef __attribute__((ext_vector_type(2))) int i32x2;

#define BSZ   8192
#define DDIM  128
#define NCLS  512
#define SLOT  48                    // max members/class supported (actual max ~34)
#define NPAN  64                    // 128-row panels
#define NTRI  (NPAN * (NPAN + 1) / 2)   // 2080 upper-triangular 128x128 tiles

#define L2E  1.44269504088896340736f
#define RLN2 0.69314718055994530942f

static __device__ __forceinline__ float fast_sqrt(float x) {
  float r; asm("v_sqrt_f32 %0, %1" : "=v"(r) : "v"(x)); return r;
}
static __device__ __forceinline__ float fast_exp2(float x) {
  float r; asm("v_exp_f32 %0, %1" : "=v"(r) : "v"(x)); return r;
}
static __device__ __forceinline__ float fast_log2(float x) {
  float r; asm("v_log_f32 %0, %1" : "=v"(r) : "v"(x)); return r;
}

static __device__ __forceinline__ void tile_ij(int t, int& bi, int& bj) {
  int j = (int)((sqrtf(8.0f * (float)t + 1.0f) - 1.0f) * 0.5f);
  while ((j + 1) * (j + 2) / 2 <= t) ++j;
  while (j * (j + 1) / 2 > t) --j;
  bi = t - j * (j + 1) / 2;
  bj = j;
}

// Decode unordered-pair linear index u -> (i, j) with j > i, for n rows.
static __device__ __forceinline__ void pair_ij(int u, int n, int& pi, int& pj) {
  float fn = (float)(2 * n - 1);
  int i = (int)((fn - fast_sqrt(fn * fn - 8.0f * (float)u)) * 0.5f);
  if (i < 0) i = 0;
  while ((i + 1) * (2 * n - i - 2) / 2 <= u) ++i;
  while (i * (2 * n - i - 1) / 2 > u) --i;
  pi = i;
  pj = i + 1 + (u - i * (2 * n - i - 1) / 2);
}

// score -> fp8(e4m3) in MFMA-FRAGMENT order + exact fp32 row magnitudes.
// Also zeroes the class ticket. (measured: 1.9 us)
__global__ void prep_kernel(const float* __restrict__ score,
                            unsigned char* __restrict__ Sfrag,
                            float* __restrict__ mag,
                            int* __restrict__ ticket) {
  int gid = blockIdx.x * 256 + threadIdx.x;   // 131072 threads
  if (gid == 0) *ticket = 0;
  int row = gid >> 4, sub = gid & 15;
  const f32x4* src = (const f32x4*)(score + (size_t)row * DDIM + sub * 8);
  f32x4 a = src[0], b = src[1];
  i32x2 pk;
  int w0 = 0, w1 = 0;
  w0 = __builtin_amdgcn_cvt_pk_fp8_f32(a[0], a[1], w0, false);
  w0 = __builtin_amdgcn_cvt_pk_fp8_f32(a[2], a[3], w0, true);
  w1 = __builtin_amdgcn_cvt_pk_fp8_f32(b[0], b[1], w1, false);
  w1 = __builtin_amdgcn_cvt_pk_fp8_f32(b[2], b[3], w1, true);
  pk[0] = w0; pk[1] = w1;
  size_t chunk = ((size_t)(row >> 4) * 4 + (sub >> 2)) * 64
               + (size_t)(sub & 3) * 16 + (row & 15);
  ((i32x2*)Sfrag)[chunk] = pk;
  float sq = a[0]*a[0] + a[1]*a[1] + a[2]*a[2] + a[3]*a[3]
           + b[0]*b[0] + b[1]*b[1] + b[2]*b[2] + b[3]*b[3];
  sq += __shfl_xor(sq, 1); sq += __shfl_xor(sq, 2);
  sq += __shfl_xor(sq, 4); sq += __shfl_xor(sq, 8);
  if (sub == 0) mag[row] = sq;
}

// Dense symmetric pass, VALU-diet edition (counters R21: VALUBusy 73%,
// MfmaUtil 14%, Occ 68% -> VALU-issue-bound). Changes vs R17: (1) fragment
// loads via per-lane base pointer + compile-time byte offsets (kills 64-bit
// address chains); (2) packed-f32 epilogue (pk_add/pk_fma/pk_max on the
// (e0,e1) pair). Same math, same layout, partials to P.
__launch_bounds__(512, 8)
__global__ void dense_pass(const unsigned char* __restrict__ Sfrag,
                           const float* __restrict__ mag,
                           float* __restrict__ P) {
  const int t = blockIdx.x;
  int bi, bj; tile_ij(t, bi, bj);
  const int i0 = bi * 128, j0 = bj * 128;
  const bool diag = (bi == bj);

  __shared__ float Lrow[128][4];
  __shared__ float Lcol[128][2];

  const int tid = threadIdx.x;
  const int wid = tid >> 6, l = tid & 63;
  const int wr = wid >> 2, wc = wid & 3;       // 2x4 wave grid: 64x32 tiles
  const int lr = l >> 4, lc = l & 15;

  // per-lane byte bases; all 24 loads use compile-time offsets from these
  const char* baseA = (const char*)Sfrag
      + (size_t)((i0 >> 4) + wr * 4) * 2048 + (size_t)l * 8;
  const char* baseB = (const char*)Sfrag
      + (size_t)((j0 >> 4) + wc * 2) * 2048 + (size_t)l * 8;

  f32x4 acc[4][2] = {};
  #pragma unroll
  for (int ks = 0; ks < 4; ++ks) {
    long af[4], bfr[2];
    #pragma unroll
    for (int m = 0; m < 4; ++m)
      af[m] = *(const long*)(baseA + m * 2048 + ks * 512);
    #pragma unroll
    for (int n = 0; n < 2; ++n)
      bfr[n] = *(const long*)(baseB + n * 2048 + ks * 512);
    #pragma unroll
    for (int m = 0; m < 4; ++m)
      #pragma unroll
      for (int n = 0; n < 2; ++n)
        acc[m][n] = __builtin_amdgcn_mfma_f32_16x16x32_fp8_fp8(
            af[m], bfr[n], acc[m][n], 0, 0, 0);
  }

  const f32x2 magj = {mag[j0 + wc * 32 + lc], mag[j0 + wc * 32 + 16 + lc]};
  f32x2 cs = {0.0f, 0.0f};

  #pragma unroll
  for (int m = 0; m < 4; ++m) {
    const f32x4 mi = *(const f32x4*)&mag[i0 + wr * 64 + m * 16 + lr * 4];
    #pragma unroll
    for (int rg = 0; rg < 4; ++rg) {
      // C layout: col = lane&15, row = (lane>>4)*4 + reg
      const int rrow = wr * 64 + m * 16 + lr * 4 + rg;
      f32x2 av = {acc[m][0][rg], acc[m][1][rg]};
      f32x2 mm = {mi[rg], mi[rg]};
      f32x2 d2 = mm + magj + (-2.0f) * av;           // pk_add + pk_fma
      d2 = __builtin_elementwise_max(d2, (f32x2){0.0f, 0.0f});  // pk_max
      float e0 = fast_exp2(__builtin_fmaf(-L2E, fast_sqrt(d2[0]), L2E));
      float e1 = fast_exp2(__builtin_fmaf(-L2E, fast_sqrt(d2[1]), L2E));
      if (diag) {
        if (rrow == wc * 32 + lc) e0 = 0.0f;        // exclude i == j
        if (rrow == wc * 32 + 16 + lc) e1 = 0.0f;
      }
      f32x2 ev = {e0, e1};
      cs += ev;                                      // pk_add
      float v = e0 + e1;
      v += __shfl_xor(v, 1); v += __shfl_xor(v, 2);
      v += __shfl_xor(v, 4); v += __shfl_xor(v, 8);
      if (lc == 0) Lrow[rrow][wc] = v;
    }
  }
  if (!diag) {
    float v0 = cs[0], v1 = cs[1];
    v0 += __shfl_xor(v0, 16); v0 += __shfl_xor(v0, 32);
    v1 += __shfl_xor(v1, 16); v1 += __shfl_xor(v1, 32);
    if (lr == 0) {
      Lcol[wc * 32 + lc][wr] = v0;
      Lcol[wc * 32 + 16 + lc][wr] = v1;
    }
  }
  __syncthreads();
  float* Pt = P + (size_t)t * 256;
  if (tid < 128)
    Pt[tid] = Lrow[tid][0] + Lrow[tid][1] + Lrow[tid][2] + Lrow[tid][3];
  else if (tid < 256 && !diag)
    Pt[tid] = Lcol[tid - 128][0] + Lcol[tid - 128][1];
}

// Per-class pass + final reduce (byte-identical to R17; measured 15.9 us).
__launch_bounds__(512)
__global__ void class_pass(const float* __restrict__ score,
                           const float* __restrict__ mag,
                           const float* __restrict__ P,
                           const int* __restrict__ targets,
                           float* __restrict__ partial,
                           int* __restrict__ ticket,
                           float* __restrict__ out) {
  const int c = blockIdx.x;
  const int tid = threadIdx.x;
  __shared__ int mem[SLOT];
  __shared__ int nCnt;
  __shared__ int lastFlag;
  __shared__ float rows[SLOT][132];   // [.][128] holds mag
  __shared__ float Nf[SLOT];
  __shared__ float Ns[SLOT];
  __shared__ float dmat[SLOT * SLOT];
  __shared__ float redL[8], redC[8];

  if (tid == 0) nCnt = 0;
  __syncthreads();
  // member discovery: vectorized coalesced scan + LDS atomic append
  for (int rd = 0; rd < BSZ / 2048; ++rd) {
    int v4 = rd * 512 + tid;
    i32x4 tv = ((const i32x4*)targets)[v4];
    #pragma unroll
    for (int q = 0; q < 4; ++q) {
      if (tv[q] == c) {
        int p = atomicAdd(&nCnt, 1);
        if (p < SLOT) mem[p] = v4 * 4 + q;
      }
    }
  }
  __syncthreads();
  const int n = nCnt < SLOT ? nCnt : SLOT;

  float ll = 0.0f, lcn = 0.0f;
  if (n >= 2) {
    for (int i = tid; i < n; i += 512) { Ns[i] = 0.0f; Nf[i] = 0.0f; }
    __syncthreads();
    for (int w = tid; w < n * 32; w += 512) {
      int i = w >> 5, ch = w & 31;
      *(f32x4*)&rows[i][ch * 4] =
          *(const f32x4*)(score + (size_t)mem[i] * DDIM + ch * 4);
    }
    for (int i = tid; i < n; i += 512) rows[i][128] = mag[mem[i]];
    // gather Nfull from the 64 panel partials per member
    for (int w = tid; w < n * 64; w += 512) {
      int i = w >> 6, q = w & 63;
      int gi = mem[i], pp = gi >> 7, off = gi & 127;
      float v = (q >= pp) ? P[(size_t)(q * (q + 1) / 2 + pp) * 256 + off]
                          : P[(size_t)(pp * (pp + 1) / 2 + q) * 256 + 128 + off];
      atomicAdd(&Nf[i], v);
    }
    __syncthreads();
    const int npu = n * (n - 1) / 2;          // unordered pairs, j > i
    for (int u = tid; u < npu; u += 512) {
      int i, j; pair_ij(u, n, i, j);
      float dot = 0.0f;
      #pragma unroll
      for (int k = 0; k < 32; ++k) {
        f32x4 a = *(const f32x4*)&rows[i][k * 4];
        f32x4 b = *(const f32x4*)&rows[j][k * 4];
        dot += a[0]*b[0] + a[1]*b[1] + a[2]*b[2] + a[3]*b[3];
      }
      float d2 = fmaxf(rows[i][128] + rows[j][128] - 2.0f * dot, 0.0f);
      float dd = fast_sqrt(d2);
      dmat[i * SLOT + j] = dd;
      float e = fast_exp2(__builtin_fmaf(-L2E, dd, L2E));
      atomicAdd(&Ns[i], e);
      atomicAdd(&Ns[j], e);
    }
    __syncthreads();
    for (int i = tid; i < n; i += 512) Nf[i] -= Ns[i];
    __syncthreads();
    for (int u = tid; u < npu; u += 512) {
      int i, j; pair_ij(u, n, i, j);
      float ln = fast_log2(Nf[i] + Nf[j]) * RLN2 + dmat[i * SLOT + j];
      if (ln > 0.0f) ll += 2.0f * ln * ln;    // both orientations
      lcn += 2.0f;
    }
  }
  #pragma unroll
  for (int m = 1; m < 64; m <<= 1) {
    ll  += __shfl_xor(ll, m);
    lcn += __shfl_xor(lcn, m);
  }
  if ((tid & 63) == 0) { redL[tid >> 6] = ll; redC[tid >> 6] = lcn; }
  __syncthreads();
  if (tid == 0) {
    float sl = 0.0f, sc = 0.0f;
    #pragma unroll
    for (int w = 0; w < 8; ++w) { sl += redL[w]; sc += redC[w]; }
    partial[2 * c]     = sl;
    partial[2 * c + 1] = sc;
    __threadfence();
    lastFlag = (atomicAdd(ticket, 1) == NCLS - 1);
  }
  __syncthreads();
  if (lastFlag) {
    float sl = 0.0f, sc = 0.0f;
    for (int i = tid; i < NCLS; i += 512) {
      sl += atomicAdd(&partial[2 * i], 0.0f);       // device-scope reads
      sc += atomicAdd(&partial[2 * i + 1], 0.0f);
    }
    #pragma unroll
    for (int m = 1; m < 64; m <<= 1) {
      sl += __shfl_xor(sl, m);
      sc += __shfl_xor(sc, m);
    }
    if ((tid & 63) == 0) { redL[tid >> 6] = sl; redC[tid >> 6] = sc; }
    __syncthreads();
    if (tid == 0) {
      float L = 0.0f, C = 0.0f;
      #pragma unroll
      for (int w = 0; w < 8; ++w) { L += redL[w]; C += redC[w]; }
      out[0] = L / (4.0f * C);
    }
  }
}

extern "C" void kernel_launch(void* const* d_in, const int* in_sizes, int n_in,
                              void* d_out, int out_size, void* d_ws, size_t ws_size,
                              hipStream_t stream) {
  const float* score = (const float*)d_in[0];
  const int* targets = (const int*)d_in[1];
  float* out = (float*)d_out;

  char* ws = (char*)d_ws;
  size_t cur = 0;
  auto alloc = [&](size_t bytes) -> void* {
    void* p = ws + cur;
    cur += (bytes + 255) & ~(size_t)255;
    return p;
  };
  unsigned char* Sfrag = (unsigned char*)alloc((size_t)BSZ * DDIM);
  float* mag     = (float*)alloc(BSZ * 4);
  float* P       = (float*)alloc((size_t)NTRI * 256 * 4);
  float* partial = (float*)alloc(NCLS * 2 * 4);
  int*   ticket  = (int*)alloc(4);

  prep_kernel<<<BSZ * 16 / 256, 256, 0, stream>>>(score, Sfrag, mag, ticket);
  dense_pass<<<NTRI, 512, 0, stream>>>(Sfrag, mag, P);
  class_pass<<<NCLS, 512, 0, stream>>>(score, mag, P, targets,
                                       partial, ticket, out);
}

// Round 23
// 52.980 us; speedup vs baseline: 1.2902x; 1.0393x over previous
//
#include <hip/hip_runtime.h>
#include <hip/hip_bf16.h>

typedef __attribute__((ext_vector_type(4))) float f32x4;
typedef __attribute__((ext_vector_type(4))) int i32x4;
typedef __attribute__((ext_vector_type(2))) int i32x2;

#define BSZ   8192
#define DDIM  128
#define NCLS  512
#define SLOT  48                    // max members/class supported (actual max ~34)
#define NPAN  64                    // 128-row panels
#define NTRI  (NPAN * (NPAN + 1) / 2)   // 2080 upper-triangular 128x128 tiles

#define L2E  1.44269504088896340736f
#define RLN2 0.69314718055994530942f

static __device__ __forceinline__ float fast_sqrt(float x) {
  float r; asm("v_sqrt_f32 %0, %1" : "=v"(r) : "v"(x)); return r;
}
static __device__ __forceinline__ float fast_exp2(float x) {
  float r; asm("v_exp_f32 %0, %1" : "=v"(r) : "v"(x)); return r;
}
static __device__ __forceinline__ float fast_log2(float x) {
  float r; asm("v_log_f32 %0, %1" : "=v"(r) : "v"(x)); return r;
}

static __device__ __forceinline__ void tile_ij(int t, int& bi, int& bj) {
  int j = (int)((sqrtf(8.0f * (float)t + 1.0f) - 1.0f) * 0.5f);
  while ((j + 1) * (j + 2) / 2 <= t) ++j;
  while (j * (j + 1) / 2 > t) --j;
  bi = t - j * (j + 1) / 2;
  bj = j;
}

// Decode unordered-pair linear index u -> (i, j) with j > i, for n rows.
static __device__ __forceinline__ void pair_ij(int u, int n, int& pi, int& pj) {
  float fn = (float)(2 * n - 1);
  int i = (int)((fn - fast_sqrt(fn * fn - 8.0f * (float)u)) * 0.5f);
  if (i < 0) i = 0;
  while ((i + 1) * (2 * n - i - 2) / 2 <= u) ++i;
  while (i * (2 * n - i - 1) / 2 > u) --i;
  pi = i;
  pj = i + 1 + (u - i * (2 * n - i - 1) / 2);
}

// score -> fp8(e4m3) in MFMA-FRAGMENT order + exact fp32 row magnitudes.
// Also zeroes the class ticket. (measured: 1.9 us)
__global__ void prep_kernel(const float* __restrict__ score,
                            unsigned char* __restrict__ Sfrag,
                            float* __restrict__ mag,
                            int* __restrict__ ticket) {
  int gid = blockIdx.x * 256 + threadIdx.x;   // 131072 threads
  if (gid == 0) *ticket = 0;
  int row = gid >> 4, sub = gid & 15;
  const f32x4* src = (const f32x4*)(score + (size_t)row * DDIM + sub * 8);
  f32x4 a = src[0], b = src[1];
  i32x2 pk;
  int w0 = 0, w1 = 0;
  w0 = __builtin_amdgcn_cvt_pk_fp8_f32(a[0], a[1], w0, false);
  w0 = __builtin_amdgcn_cvt_pk_fp8_f32(a[2], a[3], w0, true);
  w1 = __builtin_amdgcn_cvt_pk_fp8_f32(b[0], b[1], w1, false);
  w1 = __builtin_amdgcn_cvt_pk_fp8_f32(b[2], b[3], w1, true);
  pk[0] = w0; pk[1] = w1;
  size_t chunk = ((size_t)(row >> 4) * 4 + (sub >> 2)) * 64
               + (size_t)(sub & 3) * 16 + (row & 15);
  ((i32x2*)Sfrag)[chunk] = pk;
  float sq = a[0]*a[0] + a[1]*a[1] + a[2]*a[2] + a[3]*a[3]
           + b[0]*b[0] + b[1]*b[1] + b[2]*b[2] + b[3]*b[3];
  sq += __shfl_xor(sq, 1); sq += __shfl_xor(sq, 2);
  sq += __shfl_xor(sq, 4); sq += __shfl_xor(sq, 8);
  if (sub == 0) mag[row] = sq;
}

// Dense symmetric pass (measured 21.7 us; VALUBusy 73% / MfmaUtil 14% /
// Occ 68% -> VALU-issue-bound, best of 9 structural variants): one
// 512-thread block (2x4 waves of 64x32) per upper-triangular 128x128 tile,
// fp8 MFMA from fragment-ordered array (coalesced 512B loads, no staging
// LDS), register-diet epilogue, partials to P.
__launch_bounds__(512, 8)
__global__ void dense_pass(const unsigned char* __restrict__ Sfrag,
                           const float* __restrict__ mag,
                           float* __restrict__ P) {
  const int t = blockIdx.x;
  int bi, bj; tile_ij(t, bi, bj);
  const int i0 = bi * 128, j0 = bj * 128;
  const bool diag = (bi == bj);

  __shared__ float Lrow[128][4];
  __shared__ float Lcol[128][2];

  const int tid = threadIdx.x;
  const int wid = tid >> 6, l = tid & 63;
  const int wr = wid >> 2, wc = wid & 3;       // 2x4 wave grid: 64x32 tiles
  const int lr = l >> 4, lc = l & 15;

  const long* F = (const long*)Sfrag;          // one long = one 8B chunk
  const int pa = (i0 >> 4) + wr * 4;           // A panel16 base
  const int pb = (j0 >> 4) + wc * 2;           // B panel16 base

  f32x4 acc[4][2] = {};
  #pragma unroll
  for (int ks = 0; ks < 4; ++ks) {
    long af[4], bfr[2];
    #pragma unroll
    for (int m = 0; m < 4; ++m)
      af[m] = F[(size_t)((pa + m) * 4 + ks) * 64 + l];
    #pragma unroll
    for (int n = 0; n < 2; ++n)
      bfr[n] = F[(size_t)((pb + n) * 4 + ks) * 64 + l];
    #pragma unroll
    for (int m = 0; m < 4; ++m)
      #pragma unroll
      for (int n = 0; n < 2; ++n)
        acc[m][n] = __builtin_amdgcn_mfma_f32_16x16x32_fp8_fp8(
            af[m], bfr[n], acc[m][n], 0, 0, 0);
  }

  const float magj0 = mag[j0 + wc * 32 + lc];
  const float magj1 = mag[j0 + wc * 32 + 16 + lc];
  float cs0 = 0.0f, cs1 = 0.0f;

  #pragma unroll
  for (int m = 0; m < 4; ++m) {
    const f32x4 mi = *(const f32x4*)&mag[i0 + wr * 64 + m * 16 + lr * 4];
    #pragma unroll
    for (int rg = 0; rg < 4; ++rg) {
      // C layout: col = lane&15, row = (lane>>4)*4 + reg
      const int rrow = wr * 64 + m * 16 + lr * 4 + rg;
      float d2a = fmaxf(mi[rg] + magj0 - 2.0f * acc[m][0][rg], 0.0f);
      float e0 = fast_exp2(__builtin_fmaf(-L2E, fast_sqrt(d2a), L2E));
      float d2b = fmaxf(mi[rg] + magj1 - 2.0f * acc[m][1][rg], 0.0f);
      float e1 = fast_exp2(__builtin_fmaf(-L2E, fast_sqrt(d2b), L2E));
      if (diag) {
        if (rrow == wc * 32 + lc) e0 = 0.0f;        // exclude i == j
        if (rrow == wc * 32 + 16 + lc) e1 = 0.0f;
      }
      cs0 += e0; cs1 += e1;
      float v = e0 + e1;
      v += __shfl_xor(v, 1); v += __shfl_xor(v, 2);
      v += __shfl_xor(v, 4); v += __shfl_xor(v, 8);
      if (lc == 0) Lrow[rrow][wc] = v;
    }
  }
  if (!diag) {
    float v0 = cs0, v1 = cs1;
    v0 += __shfl_xor(v0, 16); v0 += __shfl_xor(v0, 32);
    v1 += __shfl_xor(v1, 16); v1 += __shfl_xor(v1, 32);
    if (lr == 0) {
      Lcol[wc * 32 + lc][wr] = v0;
      Lcol[wc * 32 + 16 + lc][wr] = v1;
    }
  }
  __syncthreads();
  float* Pt = P + (size_t)t * 256;
  if (tid < 128)
    Pt[tid] = Lrow[tid][0] + Lrow[tid][1] + Lrow[tid][2] + Lrow[tid][3];
  else if (tid < 256 && !diag)
    Pt[tid] = Lcol[tid - 128][0] + Lcol[tid - 128][1];
}

// Per-class pass + final reduce (measured 15.9 us; latency-structural).
__launch_bounds__(512)
__global__ void class_pass(const float* __restrict__ score,
                           const float* __restrict__ mag,
                           const float* __restrict__ P,
                           const int* __restrict__ targets,
                           float* __restrict__ partial,
                           int* __restrict__ ticket,
                           float* __restrict__ out) {
  const int c = blockIdx.x;
  const int tid = threadIdx.x;
  __shared__ int mem[SLOT];
  __shared__ int nCnt;
  __shared__ int lastFlag;
  __shared__ float rows[SLOT][132];   // [.][128] holds mag
  __shared__ float Nf[SLOT];
  __shared__ float Ns[SLOT];
  __shared__ float dmat[SLOT * SLOT];
  __shared__ float redL[8], redC[8];

  if (tid == 0) nCnt = 0;
  __syncthreads();
  // member discovery: vectorized coalesced scan + LDS atomic append
  for (int rd = 0; rd < BSZ / 2048; ++rd) {
    int v4 = rd * 512 + tid;
    i32x4 tv = ((const i32x4*)targets)[v4];
    #pragma unroll
    for (int q = 0; q < 4; ++q) {
      if (tv[q] == c) {
        int p = atomicAdd(&nCnt, 1);
        if (p < SLOT) mem[p] = v4 * 4 + q;
      }
    }
  }
  __syncthreads();
  const int n = nCnt < SLOT ? nCnt : SLOT;

  float ll = 0.0f, lcn = 0.0f;
  if (n >= 2) {
    for (int i = tid; i < n; i += 512) { Ns[i] = 0.0f; Nf[i] = 0.0f; }
    __syncthreads();
    for (int w = tid; w < n * 32; w += 512) {
      int i = w >> 5, ch = w & 31;
      *(f32x4*)&rows[i][ch * 4] =
          *(const f32x4*)(score + (size_t)mem[i] * DDIM + ch * 4);
    }
    for (int i = tid; i < n; i += 512) rows[i][128] = mag[mem[i]];
    // gather Nfull from the 64 panel partials per member
    for (int w = tid; w < n * 64; w += 512) {
      int i = w >> 6, q = w & 63;
      int gi = mem[i], pp = gi >> 7, off = gi & 127;
      float v = (q >= pp) ? P[(size_t)(q * (q + 1) / 2 + pp) * 256 + off]
                          : P[(size_t)(pp * (pp + 1) / 2 + q) * 256 + 128 + off];
      atomicAdd(&Nf[i], v);
    }
    __syncthreads();
    const int npu = n * (n - 1) / 2;          // unordered pairs, j > i
    for (int u = tid; u < npu; u += 512) {
      int i, j; pair_ij(u, n, i, j);
      float dot = 0.0f;
      #pragma unroll
      for (int k = 0; k < 32; ++k) {
        f32x4 a = *(const f32x4*)&rows[i][k * 4];
        f32x4 b = *(const f32x4*)&rows[j][k * 4];
        dot += a[0]*b[0] + a[1]*b[1] + a[2]*b[2] + a[3]*b[3];
      }
      float d2 = fmaxf(rows[i][128] + rows[j][128] - 2.0f * dot, 0.0f);
      float dd = fast_sqrt(d2);
      dmat[i * SLOT + j] = dd;
      float e = fast_exp2(__builtin_fmaf(-L2E, dd, L2E));
      atomicAdd(&Ns[i], e);
      atomicAdd(&Ns[j], e);
    }
    __syncthreads();
    for (int i = tid; i < n; i += 512) Nf[i] -= Ns[i];
    __syncthreads();
    for (int u = tid; u < npu; u += 512) {
      int i, j; pair_ij(u, n, i, j);
      float ln = fast_log2(Nf[i] + Nf[j]) * RLN2 + dmat[i * SLOT + j];
      if (ln > 0.0f) ll += 2.0f * ln * ln;    // both orientations
      lcn += 2.0f;
    }
  }
  #pragma unroll
  for (int m = 1; m < 64; m <<= 1) {
    ll  += __shfl_xor(ll, m);
    lcn += __shfl_xor(lcn, m);
  }
  if ((tid & 63) == 0) { redL[tid >> 6] = ll; redC[tid >> 6] = lcn; }
  __syncthreads();
  if (tid == 0) {
    float sl = 0.0f, sc = 0.0f;
    #pragma unroll
    for (int w = 0; w < 8; ++w) { sl += redL[w]; sc += redC[w]; }
    partial[2 * c]     = sl;
    partial[2 * c + 1] = sc;
    __threadfence();
    lastFlag = (atomicAdd(ticket, 1) == NCLS - 1);
  }
  __syncthreads();
  if (lastFlag) {
    float sl = 0.0f, sc = 0.0f;
    for (int i = tid; i < NCLS; i += 512) {
      sl += atomicAdd(&partial[2 * i], 0.0f);       // device-scope reads
      sc += atomicAdd(&partial[2 * i + 1], 0.0f);
    }
    #pragma unroll
    for (int m = 1; m < 64; m <<= 1) {
      sl += __shfl_xor(sl, m);
      sc += __shfl_xor(sc, m);
    }
    if ((tid & 63) == 0) { redL[tid >> 6] = sl; redC[tid >> 6] = sc; }
    __syncthreads();
    if (tid == 0) {
      float L = 0.0f, C = 0.0f;
      #pragma unroll
      for (int w = 0; w < 8; ++w) { L += redL[w]; C += redC[w]; }
      out[0] = L / (4.0f * C);
    }
  }
}

extern "C" void kernel_launch(void* const* d_in, const int* in_sizes, int n_in,
                              void* d_out, int out_size, void* d_ws, size_t ws_size,
                              hipStream_t stream) {
  const float* score = (const float*)d_in[0];
  const int* targets = (const int*)d_in[1];
  float* out = (float*)d_out;

  char* ws = (char*)d_ws;
  size_t cur = 0;
  auto alloc = [&](size_t bytes) -> void* {
    void* p = ws + cur;
    cur += (bytes + 255) & ~(size_t)255;
    return p;
  };
  unsigned char* Sfrag = (unsigned char*)alloc((size_t)BSZ * DDIM);
  float* mag     = (float*)alloc(BSZ * 4);
  float* P       = (float*)alloc((size_t)NTRI * 256 * 4);
  float* partial = (float*)alloc(NCLS * 2 * 4);
  int*   ticket  = (int*)alloc(4);

  prep_kernel<<<BSZ * 16 / 256, 256, 0, stream>>>(score, Sfrag, mag, ticket);
  dense_pass<<<NTRI, 512, 0, stream>>>(Sfrag, mag, P);
  class_pass<<<NCLS, 512, 0, stream>>>(score, mag, P, targets,
                                       partial, ticket, out);
}